// Round 17
// baseline (580.395 us; speedup 1.0000x reference)
//
#include <hip/hip_runtime.h>

#define B_ 4
#define T_ 2048
#define C_ 2048
#define H_ 16
#define HD_ 128
#define BT_ (B_*T_)
#define N3_ (3*C_)

typedef unsigned short u16;
typedef unsigned int u32;
using short8 = __attribute__((ext_vector_type(8))) short;
using f32x4  = __attribute__((ext_vector_type(4))) float;

__device__ __forceinline__ u16 f2bf(float f) {
  union { float f; u32 u; } v; v.f = f;
  u32 r = v.u + 0x7FFFu + ((v.u >> 16) & 1u);
  return (u16)(r >> 16);
}
__device__ __forceinline__ float bf2f(u16 u) {
  union { u32 u; float f; } v; v.u = ((u32)u) << 16;
  return v.f;
}
__device__ __forceinline__ void gload_lds16(const void* g, void* l) {
  __builtin_amdgcn_global_load_lds((const __attribute__((address_space(1))) void*)g,
                                   (__attribute__((address_space(3))) void*)l, 16, 0, 0);
}

// ---------------- cast fp32 -> bf16 ----------------
__global__ __launch_bounds__(256) void cast_f2b_kernel(const float* __restrict__ in,
                                                       u16* __restrict__ out, int n4) {
  int i = blockIdx.x * 256 + threadIdx.x;
  if (i >= n4) return;
  float4 v = ((const float4*)in)[i];
  ushort4 o;
  o.x = f2bf(v.x); o.y = f2bf(v.y); o.z = f2bf(v.z); o.w = f2bf(v.w);
  ((ushort4*)out)[i] = o;
}

// ---------------- RoPE cos/sin table [T][64] ----------------
__global__ __launch_bounds__(256) void rope_table_kernel(float* __restrict__ cosb,
                                                         float* __restrict__ sinb) {
  int i = blockIdx.x * 256 + threadIdx.x;
  int t = i >> 6, d = i & 63;
  float inv = powf(10000.0f, -(float)d / 64.0f);
  float ang = (float)t * inv;
  cosb[i] = cosf(ang);
  sinb[i] = sinf(ang);
}

// ---------------- RoPE apply + split qkv ----------------
__global__ __launch_bounds__(256) void rope_apply_kernel(const u16* __restrict__ qkv,
    const float* __restrict__ cosb, const float* __restrict__ sinb,
    u16* __restrict__ qb, u16* __restrict__ kbb,
    float* __restrict__ kout, float* __restrict__ vout) {
  int gid = blockIdx.x * 256 + threadIdx.x;   // B*T*H*64 threads
  int d = gid & 63;
  int h = (gid >> 6) & 15;
  int t = (gid >> 10) & 2047;
  int b = gid >> 21;
  const u16* row = qkv + (size_t)(b * T_ + t) * N3_;
  int base = h * HD_ + d;
  const float SCALE = 0.08838834764831845f; // 1/sqrt(128), folded into Q
  float q0 = bf2f(row[base]);
  float q1 = bf2f(row[base + 64]);
  float k0 = bf2f(row[C_ + base]);
  float k1 = bf2f(row[C_ + base + 64]);
  float v0 = bf2f(row[2*C_ + base]);
  float v1 = bf2f(row[2*C_ + base + 64]);
  float c = cosb[t * 64 + d], s = sinb[t * 64 + d];
  size_t o = ((size_t)((b * H_ + h) * T_ + t)) * HD_ + d;
  qb[o]        = f2bf((q0 * c - q1 * s) * SCALE);
  qb[o + 64]   = f2bf((q1 * c + q0 * s) * SCALE);
  float kr0 = k0 * c - k1 * s;
  float kr1 = k1 * c + k0 * s;
  kout[o]      = kr0;
  kout[o + 64] = kr1;
  kbb[o]       = f2bf(kr0);
  kbb[o + 64]  = f2bf(kr1);
  vout[o]      = v0;
  vout[o + 64] = v1;
}

// ---------------- V transpose: qkv bf16 -> Vt bf16 [B,H,hd,T] ----------------
__global__ __launch_bounds__(256) void vt_kernel(const u16* __restrict__ qkvb,
                                                 u16* __restrict__ vtb) {
  __shared__ u16 tile[64][72];
  int bid = blockIdx.x;          // bh(64) * ttile(32) * dhalf(2)
  int dh = bid & 1, tt = (bid >> 1) & 31, bh = bid >> 6;
  int b = bh >> 4, h = bh & 15;
  int tid = threadIdx.x;
  int tr = tid >> 2, tc = tid & 3;
  const u16* src = qkvb + (size_t)(b*T_ + tt*64 + tr) * N3_ + 2*C_ + h*HD_ + dh*64 + tc*16;
  short8 v0 = *(const short8*)src;
  short8 v1 = *(const short8*)(src + 8);
  #pragma unroll
  for (int j = 0; j < 8; ++j) {
    tile[tr][tc*16 + j]     = (u16)v0[j];
    tile[tr][tc*16 + 8 + j] = (u16)v1[j];
  }
  __syncthreads();
  int dr = tid >> 2, c2 = tid & 3;
  short8 o0, o1;
  #pragma unroll
  for (int j = 0; j < 8; ++j) {
    o0[j] = (short)tile[c2*16 + j][dr];
    o1[j] = (short)tile[c2*16 + 8 + j][dr];
  }
  u16* dst = vtb + ((size_t)bh * HD_ + dh*64 + dr) * T_ + tt*64 + c2*16;
  *(short8*)dst = o0;
  *(short8*)(dst + 8) = o1;
}

// ---- bf16 GEMM (exact R8/R13): 256x256, BK=64, counted-lgkm, rectangle XCD ----
template<int OUT_BF16>
__global__ __launch_bounds__(512, 2) void gemm3p_kernel(const u16* __restrict__ A,
    const u16* __restrict__ Bw, void* __restrict__ Cout, int M, int N, int K, int ntx) {
  extern __shared__ u16 ldsx[];
  int lin = blockIdx.x;
  int x = lin & 7, q = lin >> 3;
  int j = q & 31, rr = q >> 5;
  int rid = rr * 8 + x;
  int rgn = ntx >> 2;
  int rmr = rid / rgn, rnr = rid - rmr * rgn;
  int mtile = rmr * 8 + (j >> 2);
  int ntile = rnr * 4 + (j & 3);
  int tid = threadIdx.x, w = tid >> 6, l = tid & 63;
  int lr = l & 15, lg = l >> 4;
  int wr = w >> 2, wc = w & 3;
  const u16* Abase = A + (size_t)mtile * 256 * K;
  const u16* Bbase = Bw + (size_t)ntile * 256 * K;

  int srow[2], scol[2], sdst[2];
  #pragma unroll
  for (int jj = 0; jj < 2; ++jj) {
    int s = jj*512 + tid;
    srow[jj] = (s >> 6)*8 + (s & 7);
    scol[jj] = ((s >> 3) & 7) * 8;
    sdst[jj] = s * 8;
  }
  int arow[8], brow[4];
  #pragma unroll
  for (int mi = 0; mi < 8; ++mi) {
    int rho = mi*16 + lr;
    arow[mi] = (rho >> 3)*512 + (rho & 7)*8 + lg*64;
  }
  #pragma unroll
  for (int nj = 0; nj < 4; ++nj) {
    int rho = (wc & 1)*64 + nj*16 + lr;
    brow[nj] = (rho >> 3)*512 + (rho & 7)*8 + lg*64;
  }
  const int haOff = (2 + wr) * 8192;
  const int hbOff = (wc >> 1) * 8192;

  auto stageB = [&](int Tp) {
    u16* dst = ldsx + (Tp & 1) * 32768;
    const u16* g = Bbase + Tp * 64;
    #pragma unroll
    for (int jj = 0; jj < 2; ++jj)
      gload_lds16(g + (size_t)srow[jj] * K + scol[jj], dst + sdst[jj]);
    #pragma unroll
    for (int jj = 0; jj < 2; ++jj)
      gload_lds16(g + (size_t)(128 + srow[jj]) * K + scol[jj], dst + 8192 + sdst[jj]);
  };
  auto stageA = [&](int Tp) {
    u16* dst = ldsx + (Tp & 1) * 32768 + 16384;
    const u16* g = Abase + Tp * 64;
    #pragma unroll
    for (int jj = 0; jj < 2; ++jj)
      gload_lds16(g + (size_t)srow[jj] * K + scol[jj], dst + sdst[jj]);
    #pragma unroll
    for (int jj = 0; jj < 2; ++jj)
      gload_lds16(g + (size_t)(128 + srow[jj]) * K + scol[jj], dst + 8192 + sdst[jj]);
  };

  short8 am03[4][2], am47[4][2], bn01[2][2], bn23[2][2];
  auto readQ0 = [&](int T) {
    const u16* base = ldsx + (T & 1) * 32768;
    #pragma unroll
    for (int i = 0; i < 4; ++i)
      #pragma unroll
      for (int kk = 0; kk < 2; ++kk)
        am03[i][kk] = *(const short8*)(base + haOff + arow[i] + kk*256);
    #pragma unroll
    for (int jj = 0; jj < 2; ++jj)
      #pragma unroll
      for (int kk = 0; kk < 2; ++kk)
        bn01[jj][kk] = *(const short8*)(base + hbOff + brow[jj] + kk*256);
  };

  f32x4 acc[8][4];
  #pragma unroll
  for (int mi = 0; mi < 8; ++mi)
    #pragma unroll
    for (int n = 0; n < 4; ++n) acc[mi][n] = (f32x4){0.f,0.f,0.f,0.f};

  const int NT = K >> 6;
  stageB(0); stageA(0); stageB(1); stageA(1);
  asm volatile("s_waitcnt vmcnt(8)" ::: "memory");
  __builtin_amdgcn_sched_barrier(0);
  __builtin_amdgcn_s_barrier();
  readQ0(0);

  for (int T = 0; T < NT; ++T) {
    const u16* base = ldsx + (T & 1) * 32768;
    bool stg = (T + 2) < NT;
    #pragma unroll
    for (int jj = 0; jj < 2; ++jj)
      #pragma unroll
      for (int kk = 0; kk < 2; ++kk)
        bn23[jj][kk] = *(const short8*)(base + hbOff + brow[2+jj] + kk*256);
    __builtin_amdgcn_s_barrier();
    __builtin_amdgcn_s_setprio(1);
    #pragma unroll
    for (int i = 0; i < 4; ++i)
      #pragma unroll
      for (int jj = 0; jj < 2; ++jj)
        #pragma unroll
        for (int kk = 0; kk < 2; ++kk)
          acc[i][jj] = __builtin_amdgcn_mfma_f32_16x16x32_bf16(am03[i][kk], bn01[jj][kk], acc[i][jj], 0, 0, 0);
    __builtin_amdgcn_s_setprio(0);
    __builtin_amdgcn_s_barrier();
    if (stg) stageB(T + 2);
    #pragma unroll
    for (int i = 0; i < 4; ++i)
      #pragma unroll
      for (int kk = 0; kk < 2; ++kk)
        am47[i][kk] = *(const short8*)(base + haOff + arow[4+i] + kk*256);
    __builtin_amdgcn_s_barrier();
    __builtin_amdgcn_s_setprio(1);
    #pragma unroll
    for (int i = 0; i < 4; ++i)
      #pragma unroll
      for (int jj = 0; jj < 2; ++jj)
        #pragma unroll
        for (int kk = 0; kk < 2; ++kk)
          acc[i][2+jj] = __builtin_amdgcn_mfma_f32_16x16x32_bf16(am03[i][kk], bn23[jj][kk], acc[i][2+jj], 0, 0, 0);
    __builtin_amdgcn_s_setprio(0);
    __builtin_amdgcn_s_barrier();
    if (stg) {
      stageA(T + 2);
      asm volatile("s_waitcnt vmcnt(8)" ::: "memory");
    } else {
      asm volatile("s_waitcnt vmcnt(0)" ::: "memory");
    }
    __builtin_amdgcn_sched_barrier(0);
    __builtin_amdgcn_s_barrier();
    __builtin_amdgcn_s_setprio(1);
    #pragma unroll
    for (int i = 0; i < 4; ++i)
      #pragma unroll
      for (int jj = 0; jj < 2; ++jj)
        #pragma unroll
        for (int kk = 0; kk < 2; ++kk)
          acc[4+i][2+jj] = __builtin_amdgcn_mfma_f32_16x16x32_bf16(am47[i][kk], bn23[jj][kk], acc[4+i][2+jj], 0, 0, 0);
    #pragma unroll
    for (int i = 0; i < 4; ++i)
      #pragma unroll
      for (int jj = 0; jj < 2; ++jj)
        #pragma unroll
        for (int kk = 0; kk < 2; ++kk)
          acc[4+i][jj] = __builtin_amdgcn_mfma_f32_16x16x32_bf16(am47[i][kk], bn01[jj][kk], acc[4+i][jj], 0, 0, 0);
    __builtin_amdgcn_s_setprio(0);
    if (T + 1 < NT) readQ0(T + 1);
    __builtin_amdgcn_s_barrier();
  }
  #pragma unroll
  for (int mi = 0; mi < 8; ++mi)
    #pragma unroll
    for (int n = 0; n < 4; ++n)
      #pragma unroll
      for (int r = 0; r < 4; ++r) {
        int grow = mtile*256 + wr*128 + mi*16 + lg*4 + r;
        int gcol = ntile*256 + wc*64 + n*16 + lr;
        float v = acc[mi][n][r];
        if (OUT_BF16) ((u16*)Cout)[(size_t)grow * N + gcol] = f2bf(v);
        else          ((float*)Cout)[(size_t)grow * N + gcol] = v;
      }
}

// ---------------- causal flash attention (R17): shared K/V fragment reads ----------------
// Both per-block q-tiles (stH, stL) consume the SAME K/V LDS tiles; R17 reads
// each bk/bv fragment ONCE and feeds both states' MFMAs (saves ~26% of all
// K/V LDS reads on this LDS-pipe-bound kernel). P region is reused between
// states: paH is register-resident before P_L overwrites (lgkm0+sched_barrier
// fences both HW completion and compiler reordering). activeL is wave-uniform.
struct TileSt {
  short8 aq[4];
  f32x4 oacc[8];
  float m_run;
  float l_run;
};

__device__ __forceinline__ void stage_kv(const u16* kpl, const u16* vpl, int kt,
                                         u16* Kd, u16* Vd, int w, int l) {
  const u16* kTile = kpl + (size_t)kt * 64 * HD_;
  int ktOff = kt * 64;
  #pragma unroll
  for (int j = 0; j < 4; ++j) {
    int s = (j*4 + w)*64 + l;
    int g = s ^ ((s >> 4) & 7);            // K: 16 chunks/row, XOR (row&7)
    gload_lds16(kTile + (g >> 4)*HD_ + (g & 15)*8, (char*)Kd + (j*4 + w)*1024);
    int g2 = s ^ ((s >> 3) & 7);           // Vt: 8 chunks/row, XOR (d&7)
    gload_lds16(vpl + (size_t)(g2 >> 3)*T_ + ktOff + (g2 & 7)*8, (char*)Vd + (j*4 + w)*1024);
  }
}

// softmax (R13 swapped layout + T13 defer-max) for one state; writes P to Pw
// and returns the pa fragments in registers.
__device__ __forceinline__ void softmax_part(TileSt& st, f32x4 s2[4], bool diag,
    char* Pw, short8 pa[2], int lr, int lg, int w) {
  float p2[4][4];
  #pragma unroll
  for (int ct = 0; ct < 4; ++ct)
    #pragma unroll
    for (int r = 0; r < 4; ++r) {
      float sv = s2[ct][r];
      if (diag && (ct*16 + lg*4 + r) > (w*16 + lr)) sv = -INFINITY;
      p2[ct][r] = sv;
    }
  float mx = p2[0][0];
  #pragma unroll
  for (int ct = 0; ct < 4; ++ct)
    #pragma unroll
    for (int r = 0; r < 4; ++r) mx = fmaxf(mx, p2[ct][r]);
  mx = fmaxf(mx, __shfl_xor(mx, 16));
  mx = fmaxf(mx, __shfl_xor(mx, 32));
  if (!__all(mx - st.m_run <= 8.0f)) {       // T13 defer-max
    float mn = fmaxf(st.m_run, mx);
    float fac = __expf(st.m_run - mn);
    st.m_run = mn;
    st.l_run *= fac;
    float facr[4];
    #pragma unroll
    for (int r = 0; r < 4; ++r) facr[r] = __shfl(fac, lg*4 + r);
    #pragma unroll
    for (int dt = 0; dt < 8; ++dt)
      #pragma unroll
      for (int r = 0; r < 4; ++r) st.oacc[dt][r] *= facr[r];
  }
  float ls = 0.f;
  #pragma unroll
  for (int ct = 0; ct < 4; ++ct)
    #pragma unroll
    for (int r = 0; r < 4; ++r) {
      float pv = __expf(p2[ct][r] - st.m_run);
      p2[ct][r] = pv;
      ls += pv;
    }
  ls += __shfl_xor(ls, 16);
  ls += __shfl_xor(ls, 32);
  st.l_run += ls;
  #pragma unroll
  for (int ct = 0; ct < 4; ++ct) {
    u32 lo = (u32)f2bf(p2[ct][0]) | ((u32)f2bf(p2[ct][1]) << 16);
    u32 hi = (u32)f2bf(p2[ct][2]) | ((u32)f2bf(p2[ct][3]) << 16);
    int pb = (lr*128 + (ct*16 + lg*4)*2) ^ ((lr & 7) << 4);
    uint2 pk2 = {lo, hi};
    *(uint2*)(Pw + pb) = pk2;
  }
  asm volatile("s_waitcnt lgkmcnt(0)" ::: "memory");
  __builtin_amdgcn_sched_barrier(0);
  #pragma unroll
  for (int kk = 0; kk < 2; ++kk) {
    int pb = (lr*128 + (kk*32 + lg*8)*2) ^ ((lr & 7) << 4);
    pa[kk] = *(const short8*)(Pw + pb);
  }
  // pa must be HW-complete and compiler-pinned before the next state's P write
  asm volatile("s_waitcnt lgkmcnt(0)" ::: "memory");
  __builtin_amdgcn_sched_barrier(0);
}

__device__ __forceinline__ void attn_tile2(TileSt& stH, TileSt& stL, bool actL,
    bool diagH, bool diagL, const u16* Kl, const u16* Vl, char* Pw,
    int lr, int lg, int w) {
  // QK^T for both states per shared bk read
  f32x4 sH[4], sL[4];
  #pragma unroll
  for (int ct = 0; ct < 4; ++ct) {
    sH[ct] = (f32x4){0.f, 0.f, 0.f, 0.f};
    sL[ct] = (f32x4){0.f, 0.f, 0.f, 0.f};
  }
  __builtin_amdgcn_s_setprio(1);
  #pragma unroll
  for (int kg = 0; kg < 4; ++kg) {
    #pragma unroll
    for (int ct = 0; ct < 4; ++ct) {
      int krow = ct*16 + lr;
      int kbyte = (krow*256 + (kg*32 + lg*8)*2) ^ ((krow & 7) << 4);
      short8 bk = *(const short8*)((const char*)Kl + kbyte);
      sH[ct] = __builtin_amdgcn_mfma_f32_16x16x32_bf16(bk, stH.aq[kg], sH[ct], 0, 0, 0);
      if (actL)
        sL[ct] = __builtin_amdgcn_mfma_f32_16x16x32_bf16(bk, stL.aq[kg], sL[ct], 0, 0, 0);
    }
  }
  __builtin_amdgcn_s_setprio(0);
  short8 paH[2], paL[2];
  softmax_part(stH, sH, diagH, Pw, paH, lr, lg, w);
  if (actL) softmax_part(stL, sL, diagL, Pw, paL, lr, lg, w);
  // PV for both states per shared bv read
  __builtin_amdgcn_s_setprio(1);
  #pragma unroll
  for (int dt = 0; dt < 8; ++dt) {
    #pragma unroll
    for (int kk = 0; kk < 2; ++kk) {
      int vrow = dt*16 + lr;
      int vbyte = (vrow*128 + (kk*32 + lg*8)*2) ^ ((vrow & 7) << 4);
      short8 bv = *(const short8*)((const char*)Vl + vbyte);
      stH.oacc[dt] = __builtin_amdgcn_mfma_f32_16x16x32_bf16(paH[kk], bv, stH.oacc[dt], 0, 0, 0);
      if (actL)
        stL.oacc[dt] = __builtin_amdgcn_mfma_f32_16x16x32_bf16(paL[kk], bv, stL.oacc[dt], 0, 0, 0);
    }
  }
  __builtin_amdgcn_s_setprio(0);
}

__device__ __forceinline__ void write_out(TileSt& st, u16* __restrict__ ao,
                                          int b, int h, int qbase, int lr, int lg, int w) {
  float invl[4];
  #pragma unroll
  for (int r = 0; r < 4; ++r) invl[r] = 1.0f / __shfl(st.l_run, lg*4 + r);
  #pragma unroll
  for (int dt = 0; dt < 8; ++dt)
    #pragma unroll
    for (int r = 0; r < 4; ++r) {
      int t = qbase + w*16 + lg*4 + r;
      int col = h*HD_ + dt*16 + lr;
      ao[(size_t)(b * T_ + t) * C_ + col] = f2bf(st.oacc[dt][r] * invl[r]);
    }
}

__global__ __launch_bounds__(256, 2) void attn_kernel(const u16* __restrict__ qb,
    const u16* __restrict__ kb, const u16* __restrict__ vtb, u16* __restrict__ ao) {
  __shared__ u16 Kl[2][64 * 128];
  __shared__ u16 Vl[2][128 * 64];
  __shared__ u16 Pl[4][16 * 64];
  int bid0 = blockIdx.x;
  int bid = (bid0 & 7) * 128 + (bid0 >> 3);     // chunked XCD mapping (1024 % 8 == 0)
  int bh = bid >> 4, pr = bid & 15;
  int lo = pr, hi = 31 - pr;                    // paired q-tiles: lo+1 + hi+1 = 33 always
  int b = bh >> 4, h = bh & 15;
  int tid = threadIdx.x, w = tid >> 6, l = tid & 63;
  int lr = l & 15, lg = l >> 4;
  const u16* qptr = qb + (size_t)bh * T_ * HD_;
  const u16* kpl  = kb + (size_t)bh * T_ * HD_;
  const u16* vpl  = vtb + (size_t)bh * HD_ * T_;
  char* Pw = (char*)&Pl[w][0];

  TileSt stL, stH;
  #pragma unroll
  for (int kg = 0; kg < 4; ++kg) {
    stL.aq[kg] = *(const short8*)(qptr + (size_t)(lo*64 + w*16 + lr) * HD_ + kg*32 + lg*8);
    stH.aq[kg] = *(const short8*)(qptr + (size_t)(hi*64 + w*16 + lr) * HD_ + kg*32 + lg*8);
  }
  #pragma unroll
  for (int dt = 0; dt < 8; ++dt) {
    stL.oacc[dt] = (f32x4){0.f, 0.f, 0.f, 0.f};
    stH.oacc[dt] = (f32x4){0.f, 0.f, 0.f, 0.f};
  }
  stL.m_run = -INFINITY; stH.m_run = -INFINITY;
  stL.l_run = 0.f;       stH.l_run = 0.f;

  stage_kv(kpl, vpl, 0, &Kl[0][0], &Vl[0][0], w, l);
  __syncthreads();
  int cur = 0;
  for (int kt = 0; kt <= hi; ++kt) {
    if (kt < hi) stage_kv(kpl, vpl, kt + 1, &Kl[cur ^ 1][0], &Vl[cur ^ 1][0], w, l);
    attn_tile2(stH, stL, kt <= lo, kt == hi, kt == lo,
               &Kl[cur][0], &Vl[cur][0], Pw, lr, lg, w);
    __syncthreads();
    cur ^= 1;
  }
  write_out(stH, ao, b, h, hi*64, lr, lg, w);
  write_out(stL, ao, b, h, lo*64, lr, lg, w);
}

extern "C" void kernel_launch(void* const* d_in, const int* in_sizes, int n_in,
                              void* d_out, int out_size, void* d_ws, size_t ws_size,
                              hipStream_t stream) {
  const float* x     = (const float*)d_in[0];
  const float* wqkv  = (const float*)d_in[1];
  const float* w_out = (const float*)d_in[2];
  float* out = (float*)d_out;

  char* ws = (char*)d_ws;
  size_t off = 0;
  u16* xb    = (u16*)(ws + off); off += (size_t)BT_ * C_ * 2;
  u16* wqkvb = (u16*)(ws + off); off += (size_t)N3_ * C_ * 2;
  u16* woutb = (u16*)(ws + off); off += (size_t)C_ * C_ * 2;
  u16* qkvb  = (u16*)(ws + off); off += (size_t)BT_ * N3_ * 2;
  u16* qbf   = (u16*)(ws + off); off += (size_t)BT_ * C_ * 2;
  u16* aob   = (u16*)(ws + off); off += (size_t)BT_ * C_ * 2;
  u16* kbb   = (u16*)(ws + off); off += (size_t)BT_ * C_ * 2;
  u16* vtb   = (u16*)(ws + off); off += (size_t)BT_ * C_ * 2;
  float* cosb = (float*)(ws + off); off += (size_t)T_ * 64 * 4;
  float* sinb = (float*)(ws + off); off += (size_t)T_ * 64 * 4;

  float* kout = out + (size_t)BT_ * C_;
  float* vout = out + 2 * (size_t)BT_ * C_;

  hipFuncSetAttribute((const void*)gemm3p_kernel<1>,
                      hipFuncAttributeMaxDynamicSharedMemorySize, 131072);
  hipFuncSetAttribute((const void*)gemm3p_kernel<0>,
                      hipFuncAttributeMaxDynamicSharedMemorySize, 131072);

  cast_f2b_kernel<<<(BT_*C_/4)/256, 256, 0, stream>>>(x, xb, BT_*C_/4);
  cast_f2b_kernel<<<(N3_*C_/4)/256, 256, 0, stream>>>(wqkv, wqkvb, N3_*C_/4);
  cast_f2b_kernel<<<(C_*C_/4)/256, 256, 0, stream>>>(w_out, woutb, C_*C_/4);
  rope_table_kernel<<<(T_*64)/256, 256, 0, stream>>>(cosb, sinb);
  gemm3p_kernel<1><<<(N3_/256)*(BT_/256), 512, 131072, stream>>>(xb, wqkvb, qkvb, BT_, N3_, C_, N3_/256);
  rope_apply_kernel<<<(B_*T_*H_*64)/256, 256, 0, stream>>>(qkvb, cosb, sinb, qbf, kbb, kout, vout);
  vt_kernel<<<B_*H_*(T_/64)*2, 256, 0, stream>>>(qkvb, vtb);
  attn_kernel<<<B_*H_*16, 256, 0, stream>>>(qbf, kbb, vtb, aob);
  gemm3p_kernel<0><<<(C_/256)*(BT_/256), 512, 131072, stream>>>(aob, woutb, out, BT_, C_, C_, C_/256);
}

// Round 18
// 537.780 us; speedup vs baseline: 1.0792x; 1.0792x over previous
//
#include <hip/hip_runtime.h>

#define B_ 4
#define T_ 2048
#define C_ 2048
#define H_ 16
#define HD_ 128
#define BT_ (B_*T_)
#define N3_ (3*C_)

typedef unsigned short u16;
typedef unsigned int u32;
using short8 = __attribute__((ext_vector_type(8))) short;
using f32x4  = __attribute__((ext_vector_type(4))) float;

__device__ __forceinline__ u16 f2bf(float f) {
  union { float f; u32 u; } v; v.f = f;
  u32 r = v.u + 0x7FFFu + ((v.u >> 16) & 1u);
  return (u16)(r >> 16);
}
__device__ __forceinline__ float bf2f(u16 u) {
  union { u32 u; float f; } v; v.u = ((u32)u) << 16;
  return v.f;
}
__device__ __forceinline__ void gload_lds16(const void* g, void* l) {
  __builtin_amdgcn_global_load_lds((const __attribute__((address_space(1))) void*)g,
                                   (__attribute__((address_space(3))) void*)l, 16, 0, 0);
}

// ---------------- cast fp32 -> bf16 ----------------
__global__ __launch_bounds__(256) void cast_f2b_kernel(const float* __restrict__ in,
                                                       u16* __restrict__ out, int n4) {
  int i = blockIdx.x * 256 + threadIdx.x;
  if (i >= n4) return;
  float4 v = ((const float4*)in)[i];
  ushort4 o;
  o.x = f2bf(v.x); o.y = f2bf(v.y); o.z = f2bf(v.z); o.w = f2bf(v.w);
  ((ushort4*)out)[i] = o;
}

// ---------------- RoPE cos/sin table [T][64] ----------------
__global__ __launch_bounds__(256) void rope_table_kernel(float* __restrict__ cosb,
                                                         float* __restrict__ sinb) {
  int i = blockIdx.x * 256 + threadIdx.x;
  int t = i >> 6, d = i & 63;
  float inv = powf(10000.0f, -(float)d / 64.0f);
  float ang = (float)t * inv;
  cosb[i] = cosf(ang);
  sinb[i] = sinf(ang);
}

// ---------------- RoPE apply + split qkv ----------------
__global__ __launch_bounds__(256) void rope_apply_kernel(const u16* __restrict__ qkv,
    const float* __restrict__ cosb, const float* __restrict__ sinb,
    u16* __restrict__ qb, u16* __restrict__ kbb,
    float* __restrict__ kout, float* __restrict__ vout) {
  int gid = blockIdx.x * 256 + threadIdx.x;   // B*T*H*64 threads
  int d = gid & 63;
  int h = (gid >> 6) & 15;
  int t = (gid >> 10) & 2047;
  int b = gid >> 21;
  const u16* row = qkv + (size_t)(b * T_ + t) * N3_;
  int base = h * HD_ + d;
  const float SCALE = 0.08838834764831845f; // 1/sqrt(128), folded into Q
  float q0 = bf2f(row[base]);
  float q1 = bf2f(row[base + 64]);
  float k0 = bf2f(row[C_ + base]);
  float k1 = bf2f(row[C_ + base + 64]);
  float v0 = bf2f(row[2*C_ + base]);
  float v1 = bf2f(row[2*C_ + base + 64]);
  float c = cosb[t * 64 + d], s = sinb[t * 64 + d];
  size_t o = ((size_t)((b * H_ + h) * T_ + t)) * HD_ + d;
  qb[o]        = f2bf((q0 * c - q1 * s) * SCALE);
  qb[o + 64]   = f2bf((q1 * c + q0 * s) * SCALE);
  float kr0 = k0 * c - k1 * s;
  float kr1 = k1 * c + k0 * s;
  kout[o]      = kr0;
  kout[o + 64] = kr1;
  kbb[o]       = f2bf(kr0);
  kbb[o + 64]  = f2bf(kr1);
  vout[o]      = v0;
  vout[o + 64] = v1;
}

// ---------------- V transpose: qkv bf16 -> Vt bf16 [B,H,hd,T] ----------------
__global__ __launch_bounds__(256) void vt_kernel(const u16* __restrict__ qkvb,
                                                 u16* __restrict__ vtb) {
  __shared__ u16 tile[64][72];
  int bid = blockIdx.x;          // bh(64) * ttile(32) * dhalf(2)
  int dh = bid & 1, tt = (bid >> 1) & 31, bh = bid >> 6;
  int b = bh >> 4, h = bh & 15;
  int tid = threadIdx.x;
  int tr = tid >> 2, tc = tid & 3;
  const u16* src = qkvb + (size_t)(b*T_ + tt*64 + tr) * N3_ + 2*C_ + h*HD_ + dh*64 + tc*16;
  short8 v0 = *(const short8*)src;
  short8 v1 = *(const short8*)(src + 8);
  #pragma unroll
  for (int j = 0; j < 8; ++j) {
    tile[tr][tc*16 + j]     = (u16)v0[j];
    tile[tr][tc*16 + 8 + j] = (u16)v1[j];
  }
  __syncthreads();
  int dr = tid >> 2, c2 = tid & 3;
  short8 o0, o1;
  #pragma unroll
  for (int j = 0; j < 8; ++j) {
    o0[j] = (short)tile[c2*16 + j][dr];
    o1[j] = (short)tile[c2*16 + 8 + j][dr];
  }
  u16* dst = vtb + ((size_t)bh * HD_ + dh*64 + dr) * T_ + tt*64 + c2*16;
  *(short8*)dst = o0;
  *(short8*)(dst + 8) = o1;
}

// ---- bf16 GEMM (exact R8/R13): 256x256, BK=64, counted-lgkm, rectangle XCD ----
template<int OUT_BF16>
__global__ __launch_bounds__(512, 2) void gemm3p_kernel(const u16* __restrict__ A,
    const u16* __restrict__ Bw, void* __restrict__ Cout, int M, int N, int K, int ntx) {
  extern __shared__ u16 ldsx[];
  int lin = blockIdx.x;
  int x = lin & 7, q = lin >> 3;
  int j = q & 31, rr = q >> 5;
  int rid = rr * 8 + x;
  int rgn = ntx >> 2;
  int rmr = rid / rgn, rnr = rid - rmr * rgn;
  int mtile = rmr * 8 + (j >> 2);
  int ntile = rnr * 4 + (j & 3);
  int tid = threadIdx.x, w = tid >> 6, l = tid & 63;
  int lr = l & 15, lg = l >> 4;
  int wr = w >> 2, wc = w & 3;
  const u16* Abase = A + (size_t)mtile * 256 * K;
  const u16* Bbase = Bw + (size_t)ntile * 256 * K;

  int srow[2], scol[2], sdst[2];
  #pragma unroll
  for (int jj = 0; jj < 2; ++jj) {
    int s = jj*512 + tid;
    srow[jj] = (s >> 6)*8 + (s & 7);
    scol[jj] = ((s >> 3) & 7) * 8;
    sdst[jj] = s * 8;
  }
  int arow[8], brow[4];
  #pragma unroll
  for (int mi = 0; mi < 8; ++mi) {
    int rho = mi*16 + lr;
    arow[mi] = (rho >> 3)*512 + (rho & 7)*8 + lg*64;
  }
  #pragma unroll
  for (int nj = 0; nj < 4; ++nj) {
    int rho = (wc & 1)*64 + nj*16 + lr;
    brow[nj] = (rho >> 3)*512 + (rho & 7)*8 + lg*64;
  }
  const int haOff = (2 + wr) * 8192;
  const int hbOff = (wc >> 1) * 8192;

  auto stageB = [&](int Tp) {
    u16* dst = ldsx + (Tp & 1) * 32768;
    const u16* g = Bbase + Tp * 64;
    #pragma unroll
    for (int jj = 0; jj < 2; ++jj)
      gload_lds16(g + (size_t)srow[jj] * K + scol[jj], dst + sdst[jj]);
    #pragma unroll
    for (int jj = 0; jj < 2; ++jj)
      gload_lds16(g + (size_t)(128 + srow[jj]) * K + scol[jj], dst + 8192 + sdst[jj]);
  };
  auto stageA = [&](int Tp) {
    u16* dst = ldsx + (Tp & 1) * 32768 + 16384;
    const u16* g = Abase + Tp * 64;
    #pragma unroll
    for (int jj = 0; jj < 2; ++jj)
      gload_lds16(g + (size_t)srow[jj] * K + scol[jj], dst + sdst[jj]);
    #pragma unroll
    for (int jj = 0; jj < 2; ++jj)
      gload_lds16(g + (size_t)(128 + srow[jj]) * K + scol[jj], dst + 8192 + sdst[jj]);
  };

  short8 am03[4][2], am47[4][2], bn01[2][2], bn23[2][2];
  auto readQ0 = [&](int T) {
    const u16* base = ldsx + (T & 1) * 32768;
    #pragma unroll
    for (int i = 0; i < 4; ++i)
      #pragma unroll
      for (int kk = 0; kk < 2; ++kk)
        am03[i][kk] = *(const short8*)(base + haOff + arow[i] + kk*256);
    #pragma unroll
    for (int jj = 0; jj < 2; ++jj)
      #pragma unroll
      for (int kk = 0; kk < 2; ++kk)
        bn01[jj][kk] = *(const short8*)(base + hbOff + brow[jj] + kk*256);
  };

  f32x4 acc[8][4];
  #pragma unroll
  for (int mi = 0; mi < 8; ++mi)
    #pragma unroll
    for (int n = 0; n < 4; ++n) acc[mi][n] = (f32x4){0.f,0.f,0.f,0.f};

  const int NT = K >> 6;
  stageB(0); stageA(0); stageB(1); stageA(1);
  asm volatile("s_waitcnt vmcnt(8)" ::: "memory");
  __builtin_amdgcn_sched_barrier(0);
  __builtin_amdgcn_s_barrier();
  readQ0(0);

  for (int T = 0; T < NT; ++T) {
    const u16* base = ldsx + (T & 1) * 32768;
    bool stg = (T + 2) < NT;
    #pragma unroll
    for (int jj = 0; jj < 2; ++jj)
      #pragma unroll
      for (int kk = 0; kk < 2; ++kk)
        bn23[jj][kk] = *(const short8*)(base + hbOff + brow[2+jj] + kk*256);
    __builtin_amdgcn_s_barrier();
    __builtin_amdgcn_s_setprio(1);
    #pragma unroll
    for (int i = 0; i < 4; ++i)
      #pragma unroll
      for (int jj = 0; jj < 2; ++jj)
        #pragma unroll
        for (int kk = 0; kk < 2; ++kk)
          acc[i][jj] = __builtin_amdgcn_mfma_f32_16x16x32_bf16(am03[i][kk], bn01[jj][kk], acc[i][jj], 0, 0, 0);
    __builtin_amdgcn_s_setprio(0);
    __builtin_amdgcn_s_barrier();
    if (stg) stageB(T + 2);
    #pragma unroll
    for (int i = 0; i < 4; ++i)
      #pragma unroll
      for (int kk = 0; kk < 2; ++kk)
        am47[i][kk] = *(const short8*)(base + haOff + arow[4+i] + kk*256);
    __builtin_amdgcn_s_barrier();
    __builtin_amdgcn_s_setprio(1);
    #pragma unroll
    for (int i = 0; i < 4; ++i)
      #pragma unroll
      for (int jj = 0; jj < 2; ++jj)
        #pragma unroll
        for (int kk = 0; kk < 2; ++kk)
          acc[i][2+jj] = __builtin_amdgcn_mfma_f32_16x16x32_bf16(am03[i][kk], bn23[jj][kk], acc[i][2+jj], 0, 0, 0);
    __builtin_amdgcn_s_setprio(0);
    __builtin_amdgcn_s_barrier();
    if (stg) {
      stageA(T + 2);
      asm volatile("s_waitcnt vmcnt(8)" ::: "memory");
    } else {
      asm volatile("s_waitcnt vmcnt(0)" ::: "memory");
    }
    __builtin_amdgcn_sched_barrier(0);
    __builtin_amdgcn_s_barrier();
    __builtin_amdgcn_s_setprio(1);
    #pragma unroll
    for (int i = 0; i < 4; ++i)
      #pragma unroll
      for (int jj = 0; jj < 2; ++jj)
        #pragma unroll
        for (int kk = 0; kk < 2; ++kk)
          acc[4+i][2+jj] = __builtin_amdgcn_mfma_f32_16x16x32_bf16(am47[i][kk], bn23[jj][kk], acc[4+i][2+jj], 0, 0, 0);
    #pragma unroll
    for (int i = 0; i < 4; ++i)
      #pragma unroll
      for (int jj = 0; jj < 2; ++jj)
        #pragma unroll
        for (int kk = 0; kk < 2; ++kk)
          acc[4+i][jj] = __builtin_amdgcn_mfma_f32_16x16x32_bf16(am47[i][kk], bn01[jj][kk], acc[4+i][jj], 0, 0, 0);
    __builtin_amdgcn_s_setprio(0);
    if (T + 1 < NT) readQ0(T + 1);
    __builtin_amdgcn_s_barrier();
  }
  #pragma unroll
  for (int mi = 0; mi < 8; ++mi)
    #pragma unroll
    for (int n = 0; n < 4; ++n)
      #pragma unroll
      for (int r = 0; r < 4; ++r) {
        int grow = mtile*256 + wr*128 + mi*16 + lg*4 + r;
        int gcol = ntile*256 + wc*64 + n*16 + lr;
        float v = acc[mi][n][r];
        if (OUT_BF16) ((u16*)Cout)[(size_t)grow * N + gcol] = f2bf(v);
        else          ((float*)Cout)[(size_t)grow * N + gcol] = v;
      }
}

// ---------------- causal flash attention: swapped-QK^T + defer-max (R16) ----------------
struct TileSt {
  short8 aq[4];
  f32x4 oacc[8];
  float m_run;
  float l_run;
};

__device__ __forceinline__ void stage_kv(const u16* kpl, const u16* vpl, int kt,
                                         u16* Kd, u16* Vd, int w, int l) {
  const u16* kTile = kpl + (size_t)kt * 64 * HD_;
  int ktOff = kt * 64;
  #pragma unroll
  for (int j = 0; j < 4; ++j) {
    int s = (j*4 + w)*64 + l;
    int g = s ^ ((s >> 4) & 7);            // K: 16 chunks/row, XOR (row&7)
    gload_lds16(kTile + (g >> 4)*HD_ + (g & 15)*8, (char*)Kd + (j*4 + w)*1024);
    int g2 = s ^ ((s >> 3) & 7);           // Vt: 8 chunks/row, XOR (d&7)
    gload_lds16(vpl + (size_t)(g2 >> 3)*T_ + ktOff + (g2 & 7)*8, (char*)Vd + (j*4 + w)*1024);
  }
}

__device__ __forceinline__ void attn_tile(TileSt& st, const u16* Kl, const u16* Vl,
                                          char* Pw, bool diag, int lr, int lg, int w) {
  f32x4 s2[4];
  #pragma unroll
  for (int ct = 0; ct < 4; ++ct) s2[ct] = (f32x4){0.f, 0.f, 0.f, 0.f};
  __builtin_amdgcn_s_setprio(1);
  #pragma unroll
  for (int kg = 0; kg < 4; ++kg) {
    #pragma unroll
    for (int ct = 0; ct < 4; ++ct) {
      int krow = ct*16 + lr;
      int kbyte = (krow*256 + (kg*32 + lg*8)*2) ^ ((krow & 7) << 4);
      short8 bk = *(const short8*)((const char*)Kl + kbyte);
      s2[ct] = __builtin_amdgcn_mfma_f32_16x16x32_bf16(bk, st.aq[kg], s2[ct], 0, 0, 0);
    }
  }
  __builtin_amdgcn_s_setprio(0);
  float p2[4][4];
  #pragma unroll
  for (int ct = 0; ct < 4; ++ct)
    #pragma unroll
    for (int r = 0; r < 4; ++r) {
      float sv = s2[ct][r];
      if (diag && (ct*16 + lg*4 + r) > (w*16 + lr)) sv = -INFINITY;
      p2[ct][r] = sv;
    }
  float mx = p2[0][0];
  #pragma unroll
  for (int ct = 0; ct < 4; ++ct)
    #pragma unroll
    for (int r = 0; r < 4; ++r) mx = fmaxf(mx, p2[ct][r]);
  mx = fmaxf(mx, __shfl_xor(mx, 16));
  mx = fmaxf(mx, __shfl_xor(mx, 32));
  // T13 defer-max: only rescale when some row's max grew by > 8.
  if (!__all(mx - st.m_run <= 8.0f)) {
    float mn = fmaxf(st.m_run, mx);
    float fac = __expf(st.m_run - mn);
    st.m_run = mn;
    st.l_run *= fac;
    float facr[4];
    #pragma unroll
    for (int r = 0; r < 4; ++r) facr[r] = __shfl(fac, lg*4 + r);
    #pragma unroll
    for (int dt = 0; dt < 8; ++dt)
      #pragma unroll
      for (int r = 0; r < 4; ++r) st.oacc[dt][r] *= facr[r];
  }
  float ls = 0.f;
  #pragma unroll
  for (int ct = 0; ct < 4; ++ct)
    #pragma unroll
    for (int r = 0; r < 4; ++r) {
      float pv = __expf(p2[ct][r] - st.m_run);
      p2[ct][r] = pv;
      ls += pv;
    }
  ls += __shfl_xor(ls, 16);
  ls += __shfl_xor(ls, 32);
  st.l_run += ls;
  #pragma unroll
  for (int ct = 0; ct < 4; ++ct) {
    u32 lo = (u32)f2bf(p2[ct][0]) | ((u32)f2bf(p2[ct][1]) << 16);
    u32 hi = (u32)f2bf(p2[ct][2]) | ((u32)f2bf(p2[ct][3]) << 16);
    int pb = (lr*128 + (ct*16 + lg*4)*2) ^ ((lr & 7) << 4);
    uint2 pk2 = {lo, hi};
    *(uint2*)(Pw + pb) = pk2;
  }
  asm volatile("s_waitcnt lgkmcnt(0)" ::: "memory");
  __builtin_amdgcn_sched_barrier(0);
  short8 pa[2];
  #pragma unroll
  for (int kk = 0; kk < 2; ++kk) {
    int pb = (lr*128 + (kk*32 + lg*8)*2) ^ ((lr & 7) << 4);
    pa[kk] = *(const short8*)(Pw + pb);
  }
  __builtin_amdgcn_s_setprio(1);
  #pragma unroll
  for (int dt = 0; dt < 8; ++dt) {
    #pragma unroll
    for (int kk = 0; kk < 2; ++kk) {
      int vrow = dt*16 + lr;
      int vbyte = (vrow*128 + (kk*32 + lg*8)*2) ^ ((vrow & 7) << 4);
      short8 bv = *(const short8*)((const char*)Vl + vbyte);
      st.oacc[dt] = __builtin_amdgcn_mfma_f32_16x16x32_bf16(pa[kk], bv, st.oacc[dt], 0, 0, 0);
    }
  }
  __builtin_amdgcn_s_setprio(0);
}

__device__ __forceinline__ void write_out(TileSt& st, u16* __restrict__ ao,
                                          int b, int h, int qbase, int lr, int lg, int w) {
  float invl[4];
  #pragma unroll
  for (int r = 0; r < 4; ++r) invl[r] = 1.0f / __shfl(st.l_run, lg*4 + r);
  #pragma unroll
  for (int dt = 0; dt < 8; ++dt)
    #pragma unroll
    for (int r = 0; r < 4; ++r) {
      int t = qbase + w*16 + lg*4 + r;
      int col = h*HD_ + dt*16 + lr;
      ao[(size_t)(b * T_ + t) * C_ + col] = f2bf(st.oacc[dt][r] * invl[r]);
    }
}

__global__ __launch_bounds__(256, 2) void attn_kernel(const u16* __restrict__ qb,
    const u16* __restrict__ kb, const u16* __restrict__ vtb, u16* __restrict__ ao) {
  __shared__ u16 Kl[2][64 * 128];
  __shared__ u16 Vl[2][128 * 64];
  __shared__ u16 Pl[4][16 * 64];
  int bid0 = blockIdx.x;
  int bid = (bid0 & 7) * 128 + (bid0 >> 3);     // chunked XCD mapping (1024 % 8 == 0)
  int bh = bid >> 4, pr = bid & 15;
  int lo = pr, hi = 31 - pr;                    // paired q-tiles: lo+1 + hi+1 = 33 always
  int b = bh >> 4, h = bh & 15;
  int tid = threadIdx.x, w = tid >> 6, l = tid & 63;
  int lr = l & 15, lg = l >> 4;
  const u16* qptr = qb + (size_t)bh * T_ * HD_;
  const u16* kpl  = kb + (size_t)bh * T_ * HD_;
  const u16* vpl  = vtb + (size_t)bh * HD_ * T_;
  char* Pw = (char*)&Pl[w][0];

  TileSt stL, stH;
  #pragma unroll
  for (int kg = 0; kg < 4; ++kg) {
    stL.aq[kg] = *(const short8*)(qptr + (size_t)(lo*64 + w*16 + lr) * HD_ + kg*32 + lg*8);
    stH.aq[kg] = *(const short8*)(qptr + (size_t)(hi*64 + w*16 + lr) * HD_ + kg*32 + lg*8);
  }
  #pragma unroll
  for (int dt = 0; dt < 8; ++dt) {
    stL.oacc[dt] = (f32x4){0.f, 0.f, 0.f, 0.f};
    stH.oacc[dt] = (f32x4){0.f, 0.f, 0.f, 0.f};
  }
  stL.m_run = -INFINITY; stH.m_run = -INFINITY;
  stL.l_run = 0.f;       stH.l_run = 0.f;

  stage_kv(kpl, vpl, 0, &Kl[0][0], &Vl[0][0], w, l);
  __syncthreads();
  int cur = 0;
  for (int kt = 0; kt <= hi; ++kt) {
    if (kt < hi) stage_kv(kpl, vpl, kt + 1, &Kl[cur ^ 1][0], &Vl[cur ^ 1][0], w, l);
    attn_tile(stH, &Kl[cur][0], &Vl[cur][0], Pw, kt == hi, lr, lg, w);
    if (kt <= lo) attn_tile(stL, &Kl[cur][0], &Vl[cur][0], Pw, kt == lo, lr, lg, w);
    __syncthreads();
    cur ^= 1;
  }
  write_out(stH, ao, b, h, hi*64, lr, lg, w);
  write_out(stL, ao, b, h, lo*64, lr, lg, w);
}

extern "C" void kernel_launch(void* const* d_in, const int* in_sizes, int n_in,
                              void* d_out, int out_size, void* d_ws, size_t ws_size,
                              hipStream_t stream) {
  const float* x     = (const float*)d_in[0];
  const float* wqkv  = (const float*)d_in[1];
  const float* w_out = (const float*)d_in[2];
  float* out = (float*)d_out;

  char* ws = (char*)d_ws;
  size_t off = 0;
  u16* xb    = (u16*)(ws + off); off += (size_t)BT_ * C_ * 2;
  u16* wqkvb = (u16*)(ws + off); off += (size_t)N3_ * C_ * 2;
  u16* woutb = (u16*)(ws + off); off += (size_t)C_ * C_ * 2;
  u16* qkvb  = (u16*)(ws + off); off += (size_t)BT_ * N3_ * 2;
  u16* qbf   = (u16*)(ws + off); off += (size_t)BT_ * C_ * 2;
  u16* aob   = (u16*)(ws + off); off += (size_t)BT_ * C_ * 2;
  u16* kbb   = (u16*)(ws + off); off += (size_t)BT_ * C_ * 2;
  u16* vtb   = (u16*)(ws + off); off += (size_t)BT_ * C_ * 2;
  float* cosb = (float*)(ws + off); off += (size_t)T_ * 64 * 4;
  float* sinb = (float*)(ws + off); off += (size_t)T_ * 64 * 4;

  float* kout = out + (size_t)BT_ * C_;
  float* vout = out + 2 * (size_t)BT_ * C_;

  hipFuncSetAttribute((const void*)gemm3p_kernel<1>,
                      hipFuncAttributeMaxDynamicSharedMemorySize, 131072);
  hipFuncSetAttribute((const void*)gemm3p_kernel<0>,
                      hipFuncAttributeMaxDynamicSharedMemorySize, 131072);

  cast_f2b_kernel<<<(BT_*C_/4)/256, 256, 0, stream>>>(x, xb, BT_*C_/4);
  cast_f2b_kernel<<<(N3_*C_/4)/256, 256, 0, stream>>>(wqkv, wqkvb, N3_*C_/4);
  cast_f2b_kernel<<<(C_*C_/4)/256, 256, 0, stream>>>(w_out, woutb, C_*C_/4);
  rope_table_kernel<<<(T_*64)/256, 256, 0, stream>>>(cosb, sinb);
  gemm3p_kernel<1><<<(N3_/256)*(BT_/256), 512, 131072, stream>>>(xb, wqkvb, qkvb, BT_, N3_, C_, N3_/256);
  rope_apply_kernel<<<(B_*T_*H_*64)/256, 256, 0, stream>>>(qkvb, cosb, sinb, qbf, kbb, kout, vout);
  vt_kernel<<<B_*H_*(T_/64)*2, 256, 0, stream>>>(qkvb, vtb);
  attn_kernel<<<B_*H_*16, 256, 0, stream>>>(qbf, kbb, vtb, aob);
  gemm3p_kernel<0><<<(C_/256)*(BT_/256), 512, 131072, stream>>>(aob, woutb, out, BT_, C_, C_, C_/256);
}